// Round 10
// baseline (133.978 us; speedup 1.0000x reference)
//
#include <hip/hip_runtime.h>

// x: (2,8,256,256) fp32, F: 3x3 fp32.
#define HS 256
#define WSZ 256
#define NPIX (HS * WSZ)        // 65536 pixels
#define NCH 16                 // B*C
#define NELEM (NPIX * NCH)
#define PSTRIDE 257            // s-slots (0..256) per row of P

// ---------------------------------------------------------------------------
// Prefix kernel: P[h][s][ch] = sum_{w<s} x[ch][h][w], s in [0,256].
// Layout (h, s, ch): one (h,s) boundary's 16 channels = one 64B line.
// Block = one h row; thread t: ch c = t>>4, 16-wide segment seg = t&15.
// Rebuilt every launch (d_ws is re-poisoned to 0xAA by the harness).
// ---------------------------------------------------------------------------
__global__ __launch_bounds__(256) void prefix_kernel(const float* __restrict__ x,
                                                     float* __restrict__ P) {
    int h   = blockIdx.x;
    int t   = threadIdx.x;
    int c   = t >> 4;
    int seg = t & 15;

    const float4* row4 = (const float4*)(x + (size_t)c * NPIX + h * WSZ + seg * 16);
    float4 v0 = row4[0], v1 = row4[1], v2 = row4[2], v3 = row4[3];
    float vals[16] = {v0.x, v0.y, v0.z, v0.w, v1.x, v1.y, v1.z, v1.w,
                      v2.x, v2.y, v2.z, v2.w, v3.x, v3.y, v3.z, v3.w};

    float seg_sum = 0.0f;
#pragma unroll
    for (int k = 0; k < 16; ++k) seg_sum += vals[k];

    // inclusive scan of seg_sum over the 16 segments (lanes grouped by c)
    float incl = seg_sum;
#pragma unroll
    for (int d = 1; d < 16; d <<= 1) {
        float o = __shfl_up(incl, d, 16);
        if (seg >= d) incl += o;
    }
    float run = incl - seg_sum;    // exclusive prefix at s = seg*16

    float* Pr = P + (size_t)h * PSTRIDE * NCH;
    if (seg == 0) Pr[c] = 0.0f;    // P[h][0][c]
    int s0 = seg * 16;
#pragma unroll
    for (int k = 0; k < 16; ++k) {
        run += vals[k];
        Pr[(s0 + k + 1) * NCH + c] = run;
    }
}

// ---------------------------------------------------------------------------
// Geometry (bit-exact, verified R6): FMA-contracted einsum, f32.
// ---------------------------------------------------------------------------
struct LineGeom {
    float p, q, c;
    bool  col;
};

__device__ __forceinline__ LineGeom make_geom(const float* __restrict__ F, int pix) {
#pragma clang fp contract(off)
    int w = pix & (WSZ - 1);
    int h = pix >> 8;
    float u = (float)w, v = (float)h;
    float a = __builtin_fmaf(F[3], v, F[0] * u) + F[6];
    float b = __builtin_fmaf(F[4], v, F[1] * u) + F[7];
    float c = __builtin_fmaf(F[5], v, F[2] * u) + F[8];
    const float eps = 1e-8f;
    float bs = (fabsf(b) < eps) ? eps : b;
    float as = (fabsf(a) < eps) ? eps : a;
    LineGeom g;
    g.col = (fabsf(b) >= fabsf(a));
    g.p   = g.col ? a : b;
    g.q   = g.col ? bs : as;
    g.c   = c;
    return g;
}

// Chain (bit-exact, verified R6). Monotone in s: fma (fixed-sign p), divide by
// fixed q, negate, rintf are all monotone -> {s : Y(s)==y0} is contiguous.
__device__ __forceinline__ int chainY(const LineGeom& g, int s) {
#pragma clang fp contract(off)
    float t  = __builtin_fmaf(g.p, (float)s, g.c);
    float y  = (-t) / g.q;
    return (int)__builtin_rintf(y);
}

// ---------------------------------------------------------------------------
// Run-walk gather: thread = (pixel, channel-quad). Walk the monotone staircase
// y(s); for each run [s,e) at row y, add P[y][e]-P[y][s] (4 cq lanes share the
// two 64B lines). Run ends found by float prediction + EXACT chain verification
// (index decisions identical to the per-sample R6 kernel).
// ---------------------------------------------------------------------------
__global__ __launch_bounds__(256) void epi_gather_runs(const float4* __restrict__ P4,
                                                       const float* __restrict__ x,
                                                       const float* __restrict__ F,
                                                       float* __restrict__ out) {
    int tid = blockIdx.x * 256 + threadIdx.x;
    int cq  = tid & 3;
    int pix = tid >> 2;

    LineGeom g = make_geom(F, pix);
    float4 acc = make_float4(0.f, 0.f, 0.f, 0.f);

    if (g.col) {
        float slope = (-g.p) / g.q;
        int s  = 0;
        int yp = chainY(g, 0);
        while (s < 256) {
            int e;
            if (g.p == 0.0f || slope == 0.0f) {
                e = 256;
            } else {
                // predict first s past the yp +/- 0.5 crossing
                float tgt = (float)yp + ((slope > 0.0f) ? 0.5f : -0.5f);
                float xc  = -(__builtin_fmaf(g.q, tgt, g.c)) / g.p;
                xc = fminf(fmaxf(xc, -1.0f), 300.0f);   // tame extremes
                int e0 = (int)floorf(xc) + 1;
                e = min(max(e0, s + 1), 256);
            }
            // exact fix-up with the verified chain (monotone => contiguous)
            while (e < 256 && chainY(g, e) == yp) ++e;
            while (e > s + 1 && chainY(g, e - 1) != yp) --e;

            if (yp >= 0 && yp < HS) {
                int base = yp * PSTRIDE;
                float4 pb = P4[(base + s) * 4 + cq];
                float4 pe = P4[(base + e) * 4 + cq];
                acc.x += pe.x - pb.x;
                acc.y += pe.y - pb.y;
                acc.z += pe.z - pb.z;
                acc.w += pe.w - pb.w;
            }
            s = e;
            if (s < 256) yp = chainY(g, s);
        }
    } else {
        // Row mode (never taken for this F; kept for generic correctness):
        // x index = -(b*y + c)/a_safe per row y, sample img[:, :, y, xi].
        int ch = cq * 4;
        for (int s = 0; s < 256; ++s) {
            int xi = chainY(g, s);
            if (xi >= 0 && xi < WSZ) {
                int addr = s * WSZ + xi;
                acc.x += x[(ch + 0) * NPIX + addr];
                acc.y += x[(ch + 1) * NPIX + addr];
                acc.z += x[(ch + 2) * NPIX + addr];
                acc.w += x[(ch + 3) * NPIX + addr];
            }
        }
    }

    int ch = cq * 4;
    out[(ch + 0) * NPIX + pix] = acc.x;
    out[(ch + 1) * NPIX + pix] = acc.y;
    out[(ch + 2) * NPIX + pix] = acc.z;
    out[(ch + 3) * NPIX + pix] = acc.w;
}

// ---------------------------------------------------------------------------
// Fallback without workspace: direct per-sample gathers from (bc,h,w).
// ---------------------------------------------------------------------------
__device__ __forceinline__ int sample_row(const LineGeom& g, int s) {
#pragma clang fp contract(off)
    float sf = (float)s;
    float t  = __builtin_fmaf(g.p, sf, g.c);
    float y  = (-t) / g.q;
    float yr = __builtin_rintf(y);
    int   yi = (int)yr;
    return (yi >= 0 && yi < HS) ? yi : -1;
}

__global__ __launch_bounds__(256) void epi_gather_direct(const float* __restrict__ x,
                                                         const float* __restrict__ F,
                                                         float* __restrict__ out) {
    int tid  = blockIdx.x * 256 + threadIdx.x;
    int quad = tid & 3;
    int pix  = tid >> 2;

    LineGeom g = make_geom(F, pix);

    float4 acc = make_float4(0.f, 0.f, 0.f, 0.f);
    int base = quad * 4;

#pragma unroll 2
    for (int s = 0; s < 256; ++s) {
        int  t     = sample_row(g, s);
        bool valid = (t >= 0);
        int  tcl   = valid ? t : 0;
        int  addr  = g.col ? (tcl * WSZ + s) : (s * WSZ + tcl);
        if (valid) {
            acc.x += x[(base + 0) * NPIX + addr];
            acc.y += x[(base + 1) * NPIX + addr];
            acc.z += x[(base + 2) * NPIX + addr];
            acc.w += x[(base + 3) * NPIX + addr];
        }
    }

    out[(base + 0) * NPIX + pix] = acc.x;
    out[(base + 1) * NPIX + pix] = acc.y;
    out[(base + 2) * NPIX + pix] = acc.z;
    out[(base + 3) * NPIX + pix] = acc.w;
}

extern "C" void kernel_launch(void* const* d_in, const int* in_sizes, int n_in,
                              void* d_out, int out_size, void* d_ws, size_t ws_size,
                              hipStream_t stream) {
    const float* x   = (const float*)d_in[0];
    const float* F   = (const float*)d_in[1];
    float*       out = (float*)d_out;

    const size_t need = (size_t)HS * PSTRIDE * NCH * sizeof(float);  // 4.21 MB
    if (ws_size >= need) {
        float* P = (float*)d_ws;
        prefix_kernel<<<HS, 256, 0, stream>>>(x, P);
        epi_gather_runs<<<(NPIX * 4) / 256, 256, 0, stream>>>((const float4*)P, x, F, out);
    } else {
        epi_gather_direct<<<(NPIX * 4) / 256, 256, 0, stream>>>(x, F, out);
    }
}

// Round 11
// 132.705 us; speedup vs baseline: 1.0096x; 1.0096x over previous
//
#include <hip/hip_runtime.h>

// x: (2,8,256,256) fp32, F: 3x3 fp32.
#define HS 256
#define WSZ 256
#define NPIX (HS * WSZ)        // 65536 pixels
#define NCH 16                 // B*C
#define NELEM (NPIX * NCH)
#define PSTRIDE 257            // s-slots (0..256) per row of P

// ---------------------------------------------------------------------------
// Prefix kernel: P[h][s][ch] = sum_{w<s} x[ch][h][w], s in [0,256].
// Layout (h, s, ch): one (h,s) boundary's 16 channels = one 64B line.
// Rebuilt every launch (d_ws re-poisoned to 0xAA by the harness).
// ---------------------------------------------------------------------------
__global__ __launch_bounds__(256) void prefix_kernel(const float* __restrict__ x,
                                                     float* __restrict__ P) {
    int h   = blockIdx.x;
    int t   = threadIdx.x;
    int c   = t >> 4;
    int seg = t & 15;

    const float4* row4 = (const float4*)(x + (size_t)c * NPIX + h * WSZ + seg * 16);
    float4 v0 = row4[0], v1 = row4[1], v2 = row4[2], v3 = row4[3];
    float vals[16] = {v0.x, v0.y, v0.z, v0.w, v1.x, v1.y, v1.z, v1.w,
                      v2.x, v2.y, v2.z, v2.w, v3.x, v3.y, v3.z, v3.w};

    float seg_sum = 0.0f;
#pragma unroll
    for (int k = 0; k < 16; ++k) seg_sum += vals[k];

    float incl = seg_sum;
#pragma unroll
    for (int d = 1; d < 16; d <<= 1) {
        float o = __shfl_up(incl, d, 16);
        if (seg >= d) incl += o;
    }
    float run = incl - seg_sum;    // exclusive prefix at s = seg*16

    float* Pr = P + (size_t)h * PSTRIDE * NCH;
    if (seg == 0) Pr[c] = 0.0f;
    int s0 = seg * 16;
#pragma unroll
    for (int k = 0; k < 16; ++k) {
        run += vals[k];
        Pr[(s0 + k + 1) * NCH + c] = run;
    }
}

// ---------------------------------------------------------------------------
// Geometry (bit-exact, verified R6): FMA-contracted einsum, f32.
// ---------------------------------------------------------------------------
struct LineGeom {
    float p, q, c;
    bool  col;
};

__device__ __forceinline__ LineGeom make_geom(const float* __restrict__ F, int pix) {
#pragma clang fp contract(off)
    int w = pix & (WSZ - 1);
    int h = pix >> 8;
    float u = (float)w, v = (float)h;
    float a = __builtin_fmaf(F[3], v, F[0] * u) + F[6];
    float b = __builtin_fmaf(F[4], v, F[1] * u) + F[7];
    float c = __builtin_fmaf(F[5], v, F[2] * u) + F[8];
    const float eps = 1e-8f;
    float bs = (fabsf(b) < eps) ? eps : b;
    float as = (fabsf(a) < eps) ? eps : a;
    LineGeom g;
    g.col = (fabsf(b) >= fabsf(a));
    g.p   = g.col ? a : b;
    g.q   = g.col ? bs : as;
    g.c   = c;
    return g;
}

// Chain (bit-exact, verified R6): t = fma(p,s,c); y = (-t)/q IEEE f32; rint; i32.
__device__ __forceinline__ int chainY(const LineGeom& g, int s) {
#pragma clang fp contract(off)
    float t  = __builtin_fmaf(g.p, (float)s, g.c);
    float y  = (-t) / g.q;
    return (int)__builtin_rintf(y);
}

// ---------------------------------------------------------------------------
// Segment-telescoped prefix gather: 32 threads/pixel = quad(4) x seg(8).
// Each thread's quad-group covers samples [lo, lo+32). Lane computes the
// EXACT chain for its s = lo+quad+4k (full dedup), DPP-broadcasts y to the
// group, detects boundaries y_prev != y_cur by compare (no search), and loads
// prefix P only at boundaries/segment edges (predicated: inactive lanes issue
// no memory requests). acc = -P(y_lo,lo) + sum_bnd[P(y_prev,t)-P(y_t,t)]
// + P(y_last,hi), each term gated by row validity.
// ---------------------------------------------------------------------------
#define QUAD_BCAST(dst, src, ctrl)                                              \
    dst = __builtin_amdgcn_mov_dpp(src, ctrl, 0xf, 0xf, false)

__global__ __launch_bounds__(256) void epi_gather_seg(const float4* __restrict__ P4,
                                                      const float* __restrict__ x,
                                                      const float* __restrict__ F,
                                                      float* __restrict__ out) {
    int tid = blockIdx.x * 256 + threadIdx.x;
    int cq  = tid & 3;
    int seg = (tid >> 2) & 7;
    int pix = tid >> 5;

    LineGeom g = make_geom(F, pix);
    float4 acc = make_float4(0.f, 0.f, 0.f, 0.f);

    int lo = seg << 5;

    if (g.col) {
        // my 8 exact chains: s = lo + cq + 4k
        int t8[8];
#pragma unroll
        for (int k = 0; k < 8; ++k) t8[k] = chainY(g, lo + cq + 4 * k);

#define PADD(Y, S)                                                              \
        { int _i = (((Y) * PSTRIDE + (S)) << 2) + cq;                           \
          float4 _p = P4[_i];                                                   \
          acc.x += _p.x; acc.y += _p.y; acc.z += _p.z; acc.w += _p.w; }
#define PSUB(Y, S)                                                              \
        { int _i = (((Y) * PSTRIDE + (S)) << 2) + cq;                           \
          float4 _p = P4[_i];                                                   \
          acc.x -= _p.x; acc.y -= _p.y; acc.z -= _p.z; acc.w -= _p.w; }
#define BOUND(YA, YB, T)                                                        \
        if ((YA) != (YB)) {                                                     \
            if ((unsigned)(YA) < 256u) PADD(YA, T);                             \
            if ((unsigned)(YB) < 256u) PSUB(YB, T);                             \
        }

        int yprev;
        QUAD_BCAST(yprev, t8[0], 0x00);          // y at s = lo
        if ((unsigned)yprev < 256u) PSUB(yprev, lo);   // segment-start edge

#pragma unroll
        for (int k = 0; k < 8; ++k) {
            int y0, y1, y2, y3;
            QUAD_BCAST(y0, t8[k], 0x00);
            QUAD_BCAST(y1, t8[k], 0x55);
            QUAD_BCAST(y2, t8[k], 0xAA);
            QUAD_BCAST(y3, t8[k], 0xFF);
            int sb = lo + 4 * k;
            if (k) { BOUND(yprev, y0, sb) }
            BOUND(y0, y1, sb + 1)
            BOUND(y1, y2, sb + 2)
            BOUND(y2, y3, sb + 3)
            yprev = y3;
        }
        if ((unsigned)yprev < 256u) PADD(yprev, lo + 32);  // segment-end edge
#undef BOUND
#undef PSUB
#undef PADD
    } else {
        // Row mode (never taken for this F; generic correctness): per-sample
        // direct gathers from x over this segment's rows.
        int ch = cq * 4;
        for (int s = lo; s < lo + 32; ++s) {
            int xi = chainY(g, s);
            if ((unsigned)xi < 256u) {
                int addr = s * WSZ + xi;
                acc.x += x[(ch + 0) * NPIX + addr];
                acc.y += x[(ch + 1) * NPIX + addr];
                acc.z += x[(ch + 2) * NPIX + addr];
                acc.w += x[(ch + 3) * NPIX + addr];
            }
        }
    }

    // merge the 8 segments (lane bits 2-4)
    acc.x += __shfl_xor(acc.x, 4, 64);
    acc.y += __shfl_xor(acc.y, 4, 64);
    acc.z += __shfl_xor(acc.z, 4, 64);
    acc.w += __shfl_xor(acc.w, 4, 64);
    acc.x += __shfl_xor(acc.x, 8, 64);
    acc.y += __shfl_xor(acc.y, 8, 64);
    acc.z += __shfl_xor(acc.z, 8, 64);
    acc.w += __shfl_xor(acc.w, 8, 64);
    acc.x += __shfl_xor(acc.x, 16, 64);
    acc.y += __shfl_xor(acc.y, 16, 64);
    acc.z += __shfl_xor(acc.z, 16, 64);
    acc.w += __shfl_xor(acc.w, 16, 64);

    if (seg == 0) {
        int ch = cq * 4;
        out[(ch + 0) * NPIX + pix] = acc.x;
        out[(ch + 1) * NPIX + pix] = acc.y;
        out[(ch + 2) * NPIX + pix] = acc.z;
        out[(ch + 3) * NPIX + pix] = acc.w;
    }
}

// ---------------------------------------------------------------------------
// Fallback without workspace: direct per-sample gathers from (bc,h,w).
// ---------------------------------------------------------------------------
__device__ __forceinline__ int sample_row(const LineGeom& g, int s) {
#pragma clang fp contract(off)
    float sf = (float)s;
    float t  = __builtin_fmaf(g.p, sf, g.c);
    float y  = (-t) / g.q;
    float yr = __builtin_rintf(y);
    int   yi = (int)yr;
    return (yi >= 0 && yi < HS) ? yi : -1;
}

__global__ __launch_bounds__(256) void epi_gather_direct(const float* __restrict__ x,
                                                         const float* __restrict__ F,
                                                         float* __restrict__ out) {
    int tid  = blockIdx.x * 256 + threadIdx.x;
    int quad = tid & 3;
    int pix  = tid >> 2;

    LineGeom g = make_geom(F, pix);

    float4 acc = make_float4(0.f, 0.f, 0.f, 0.f);
    int base = quad * 4;

#pragma unroll 2
    for (int s = 0; s < 256; ++s) {
        int  t     = sample_row(g, s);
        bool valid = (t >= 0);
        int  tcl   = valid ? t : 0;
        int  addr  = g.col ? (tcl * WSZ + s) : (s * WSZ + tcl);
        if (valid) {
            acc.x += x[(base + 0) * NPIX + addr];
            acc.y += x[(base + 1) * NPIX + addr];
            acc.z += x[(base + 2) * NPIX + addr];
            acc.w += x[(base + 3) * NPIX + addr];
        }
    }

    out[(base + 0) * NPIX + pix] = acc.x;
    out[(base + 1) * NPIX + pix] = acc.y;
    out[(base + 2) * NPIX + pix] = acc.z;
    out[(base + 3) * NPIX + pix] = acc.w;
}

extern "C" void kernel_launch(void* const* d_in, const int* in_sizes, int n_in,
                              void* d_out, int out_size, void* d_ws, size_t ws_size,
                              hipStream_t stream) {
    const float* x   = (const float*)d_in[0];
    const float* F   = (const float*)d_in[1];
    float*       out = (float*)d_out;

    const size_t need = (size_t)HS * PSTRIDE * NCH * sizeof(float);  // 4.21 MB
    if (ws_size >= need) {
        float* P = (float*)d_ws;
        prefix_kernel<<<HS, 256, 0, stream>>>(x, P);
        epi_gather_seg<<<(NPIX * 32) / 256, 256, 0, stream>>>((const float4*)P, x, F, out);
    } else {
        epi_gather_direct<<<(NPIX * 4) / 256, 256, 0, stream>>>(x, F, out);
    }
}